// Round 6
// baseline (240.926 us; speedup 1.0000x reference)
//
#include <hip/hip_runtime.h>
#include <hip/hip_bf16.h>

#define D 256
#define BM 64
#define LDA 264   // As k-stride in bf16 elems (528 B rows; 16B-aligned, shift-4-bank rows)
#define LDAF 260  // f32 restage stride (1040 B rows, 16B-aligned)
#define LDK 72    // fallback-path pad

typedef __attribute__((ext_vector_type(8))) __bf16 bf16x8;
typedef __attribute__((ext_vector_type(4))) float f32x4;

__device__ __forceinline__ float bf2f(unsigned short u) {
    union { unsigned int i; float f; } c; c.i = ((unsigned int)u) << 16; return c.f;
}
__device__ __forceinline__ float bf2f_lo(unsigned int u) {
    union { unsigned int i; float f; } c; c.i = u << 16; return c.f;
}
__device__ __forceinline__ float bf2f_hi(unsigned int u) {
    union { unsigned int i; float f; } c; c.i = u & 0xffff0000u; return c.f;
}
__device__ __forceinline__ unsigned short f2bf(float f) {
    __hip_bfloat16 h = __float2bfloat16(f);
    return *reinterpret_cast<unsigned short*>(&h);
}
__device__ __forceinline__ unsigned int pack2(float lo, float hi) {
    return (unsigned int)f2bf(lo) | ((unsigned int)f2bf(hi) << 16);
}

// ======================= FAST PATH =======================

// blocks [0,nbF): feat fp32->bf16 ; [nbF,nbF+512): W->Wt[c][k] ; rest: edge histogram.
// deg must be zeroed before this kernel (hipMemsetAsync).
__global__ void k_prep(const float* __restrict__ uf, const float* __restrict__ itf,
                       const float* __restrict__ Wu, const float* __restrict__ Wi,
                       unsigned short* __restrict__ feat_bf,
                       unsigned short* __restrict__ Wt_u, unsigned short* __restrict__ Wt_i,
                       const int* __restrict__ iu_e, int Eiu,
                       const int* __restrict__ ui_e, int Eui,
                       int* __restrict__ deg, int NU,
                       size_t nfU, size_t nfTot, int nbF) {
    int b = blockIdx.x;
    if (b < nbF) {
        size_t base = ((size_t)b * 256 + threadIdx.x) * 8;
        if (base < nfTot) {
            const float* s = (base < nfU) ? (uf + base) : (itf + (base - nfU));
            float4 f0 = *(const float4*)s;
            float4 f1 = *(const float4*)(s + 4);
            ushort4 o0, o1;
            o0.x = f2bf(f0.x); o0.y = f2bf(f0.y); o0.z = f2bf(f0.z); o0.w = f2bf(f0.w);
            o1.x = f2bf(f1.x); o1.y = f2bf(f1.y); o1.z = f2bf(f1.z); o1.w = f2bf(f1.w);
            ((ushort4*)(feat_bf + base))[0] = o0;
            ((ushort4*)(feat_bf + base))[1] = o1;
        }
    } else if (b < nbF + 512) {
        int b2 = b - nbF;
        const float* W = (b2 < 256) ? Wu : Wi;
        unsigned short* Wt = (b2 < 256) ? Wt_u : Wt_i;
        int k = b2 & 255;
        int c = threadIdx.x;
        Wt[(size_t)c * 256 + k] = f2bf(W[(size_t)k * 256 + c]);
    } else {
        int e = (b - nbF - 512) * 256 + threadIdx.x;
        if (e < Eiu) {
            atomicAdd(&deg[iu_e[Eiu + e]], 1);
        } else if (e < Eiu + Eui) {
            int e2 = e - Eiu;
            atomicAdd(&deg[NU + ui_e[Eui + e2]], 1);
        }
    }
}

// per-1024-block inclusive scan of deg -> rs[i+1]; block totals -> bsums
__global__ void k_scan_block(const int* __restrict__ deg, int N,
                             int* __restrict__ rs, int* __restrict__ bsums) {
    __shared__ int s[1024];
    int base = blockIdx.x * 1024;
    int t = threadIdx.x;
    int v = (base + t < N) ? deg[base + t] : 0;
    s[t] = v;
    __syncthreads();
    for (int off = 1; off < 1024; off <<= 1) {
        int add = (t >= off) ? s[t - off] : 0;
        __syncthreads();
        s[t] += add;
        __syncthreads();
    }
    if (base + t < N) rs[base + t + 1] = s[t];
    if (t == 1023) bsums[blockIdx.x] = s[1023];
}

// exclusive scan of block sums (nb <= 1024)
__global__ void k_scan_sums(int* __restrict__ bsums, int nb) {
    __shared__ int s[1024];
    int t = threadIdx.x;
    int v = (t < nb) ? bsums[t] : 0;
    s[t] = v;
    __syncthreads();
    for (int off = 1; off < 1024; off <<= 1) {
        int add = (t >= off) ? s[t - off] : 0;
        __syncthreads();
        s[t] += add;
        __syncthreads();
    }
    if (t < nb) bsums[t] = s[t] - v;
}

// finalize rs and cursor: thread i owns rs[i+1], cur[i+1]; no races.
__global__ void k_finalize(int N, int* __restrict__ rs, int* __restrict__ cur,
                           const int* __restrict__ bsums) {
    int i = blockIdx.x * blockDim.x + threadIdx.x;
    if (i < N) {
        int v = rs[i + 1] + bsums[i >> 10];
        rs[i + 1] = v;
        cur[i + 1] = v;
    }
    if (i == 0) { rs[0] = 0; cur[0] = 0; }
}

// fill unified csr: user targets land in [0,Eiu), item targets in [Eiu,Etot)
__global__ void k_fill2(const int* __restrict__ iu_e, int Eiu,
                        const int* __restrict__ ui_e, int Eui,
                        int* __restrict__ cur, int NU,
                        int* __restrict__ csr) {
    int e = blockIdx.x * blockDim.x + threadIdx.x;
    if (e < Eiu) {
        int d = iu_e[Eiu + e];
        int p = atomicAdd(&cur[d], 1);
        csr[p] = iu_e[e];
    } else if (e < Eiu + Eui) {
        int e2 = e - Eiu;
        int d = ui_e[Eui + e2];
        int p = atomicAdd(&cur[NU + d], 1);
        csr[p] = ui_e[e2];
    }
}

// ---- FUSED: gather-mean -> LDS A-tile -> bf16 MFMA GEMM (B direct from L2)
//      -> bias+ReLU+LayerNorm -> coalesced float4 store (LDS restage).
// 64 rows per block, 256 threads (4 waves).
__launch_bounds__(256)
__global__ void k_fused(const unsigned short* __restrict__ uf_bf,
                        const unsigned short* __restrict__ if_bf,
                        const unsigned short* __restrict__ Wt_u,
                        const unsigned short* __restrict__ Wt_i,
                        const int* __restrict__ rs, const int* __restrict__ csr,
                        const float* __restrict__ bu, const float* __restrict__ bi,
                        const float* __restrict__ gamma, const float* __restrict__ beta,
                        int NU, int NI, int nbU, float* __restrict__ out) {
    __shared__ __align__(16) __hip_bfloat16 As[BM][LDA];   // 33792 B
    __shared__ float red_s[BM][4];                          // 1024 B
    __shared__ float red_q[BM][4];                          // 1024 B

    int b = blockIdx.x;
    bool isU = b < nbU;
    const unsigned short* srcT = isU ? if_bf : uf_bf;
    const unsigned short* tgtT = isU ? uf_bf : if_bf;
    const unsigned short* Wt   = isU ? Wt_u : Wt_i;
    const float* bias          = isU ? bu : bi;
    float* Y                   = isU ? out : out + (size_t)NU * D;
    int N                      = isU ? NU : NI;
    int row0 = (isU ? b : b - nbU) * BM;
    int wvBase = (isU ? 0 : NU) + row0;

    int t = threadIdx.x;
    int lane = t & 63;
    int w = t >> 6;
    int l15 = lane & 15;
    int l4 = lane >> 4;
    int half = lane >> 5;
    int hl = lane & 31;

    // ---- Phase A: gather + combine -> As (bf16). 2 rows per wave (half-wave each),
    //      4-unrolled edge loop -> up to 8 independent row-loads in flight per wave.
    for (int it = 0; it < 8; ++it) {
        int lrow = (it * 4 + w) * 2 + half;
        int grow = row0 + lrow;
        if (grow < N) {
            int wv = wvBase + lrow;
            int s0 = rs[wv], s1 = rs[wv + 1];
            float a0[8] = {}, a1[8] = {}, a2[8] = {}, a3[8] = {};
            int i = s0;
            for (; i + 4 <= s1; i += 4) {
                int e0 = csr[i], e1 = csr[i + 1], e2 = csr[i + 2], e3 = csr[i + 3];
                uint4 r0 = ((const uint4*)(srcT + (size_t)e0 * D))[hl];
                uint4 r1 = ((const uint4*)(srcT + (size_t)e1 * D))[hl];
                uint4 r2 = ((const uint4*)(srcT + (size_t)e2 * D))[hl];
                uint4 r3 = ((const uint4*)(srcT + (size_t)e3 * D))[hl];
                a0[0] += bf2f_lo(r0.x); a0[1] += bf2f_hi(r0.x); a0[2] += bf2f_lo(r0.y); a0[3] += bf2f_hi(r0.y);
                a0[4] += bf2f_lo(r0.z); a0[5] += bf2f_hi(r0.z); a0[6] += bf2f_lo(r0.w); a0[7] += bf2f_hi(r0.w);
                a1[0] += bf2f_lo(r1.x); a1[1] += bf2f_hi(r1.x); a1[2] += bf2f_lo(r1.y); a1[3] += bf2f_hi(r1.y);
                a1[4] += bf2f_lo(r1.z); a1[5] += bf2f_hi(r1.z); a1[6] += bf2f_lo(r1.w); a1[7] += bf2f_hi(r1.w);
                a2[0] += bf2f_lo(r2.x); a2[1] += bf2f_hi(r2.x); a2[2] += bf2f_lo(r2.y); a2[3] += bf2f_hi(r2.y);
                a2[4] += bf2f_lo(r2.z); a2[5] += bf2f_hi(r2.z); a2[6] += bf2f_lo(r2.w); a2[7] += bf2f_hi(r2.w);
                a3[0] += bf2f_lo(r3.x); a3[1] += bf2f_hi(r3.x); a3[2] += bf2f_lo(r3.y); a3[3] += bf2f_hi(r3.y);
                a3[4] += bf2f_lo(r3.z); a3[5] += bf2f_hi(r3.z); a3[6] += bf2f_lo(r3.w); a3[7] += bf2f_hi(r3.w);
            }
            for (; i < s1; ++i) {
                int e0 = csr[i];
                uint4 r0 = ((const uint4*)(srcT + (size_t)e0 * D))[hl];
                a0[0] += bf2f_lo(r0.x); a0[1] += bf2f_hi(r0.x); a0[2] += bf2f_lo(r0.y); a0[3] += bf2f_hi(r0.y);
                a0[4] += bf2f_lo(r0.z); a0[5] += bf2f_hi(r0.z); a0[6] += bf2f_lo(r0.w); a0[7] += bf2f_hi(r0.w);
            }
            int cnt = s1 - s0;
            float inv = 1.0f / (float)(cnt > 0 ? cnt : 1);
            uint4 tv = ((const uint4*)(tgtT + (size_t)grow * D))[hl];
            float x0 = bf2f_lo(tv.x) + (a0[0] + a1[0] + a2[0] + a3[0]) * inv;
            float x1 = bf2f_hi(tv.x) + (a0[1] + a1[1] + a2[1] + a3[1]) * inv;
            float x2 = bf2f_lo(tv.y) + (a0[2] + a1[2] + a2[2] + a3[2]) * inv;
            float x3 = bf2f_hi(tv.y) + (a0[3] + a1[3] + a2[3] + a3[3]) * inv;
            float x4 = bf2f_lo(tv.z) + (a0[4] + a1[4] + a2[4] + a3[4]) * inv;
            float x5 = bf2f_hi(tv.z) + (a0[5] + a1[5] + a2[5] + a3[5]) * inv;
            float x6 = bf2f_lo(tv.w) + (a0[6] + a1[6] + a2[6] + a3[6]) * inv;
            float x7 = bf2f_hi(tv.w) + (a0[7] + a1[7] + a2[7] + a3[7]) * inv;
            uint4 o;
            o.x = pack2(x0, x1); o.y = pack2(x2, x3); o.z = pack2(x4, x5); o.w = pack2(x6, x7);
            *(uint4*)&As[lrow][hl * 8] = o;
        } else {
            uint4 z = {0, 0, 0, 0};
            *(uint4*)&As[lrow][hl * 8] = z;
        }
    }

    f32x4 acc[4][4];
    f32x4 zero = {0.f, 0.f, 0.f, 0.f};
    #pragma unroll
    for (int fr = 0; fr < 4; fr++)
        #pragma unroll
        for (int fc = 0; fc < 4; fc++)
            acc[fr][fc] = zero;

    __syncthreads();

    // ---- Phase B: GEMM. A from LDS; B fragments straight from L2 (W resident).
    //      No barriers: As is read-only from here to the epilogue.
    const uint4* Bg = (const uint4*)Wt;   // Wt[col][k]: uint4 index = col*32 + k/8
    int colB = w * 64 + l15;
    #pragma unroll
    for (int ks8 = 0; ks8 < 8; ++ks8) {
        uint4 bq[4];
        #pragma unroll
        for (int fc = 0; fc < 4; ++fc)
            bq[fc] = Bg[(size_t)(colB + fc * 16) * 32 + ks8 * 4 + l4];
        bf16x8 af[4];
        #pragma unroll
        for (int fr = 0; fr < 4; ++fr)
            af[fr] = *(const bf16x8*)&As[fr * 16 + l15][ks8 * 32 + l4 * 8];
        #pragma unroll
        for (int fr = 0; fr < 4; ++fr)
            #pragma unroll
            for (int fc = 0; fc < 4; ++fc)
                acc[fr][fc] = __builtin_amdgcn_mfma_f32_16x16x32_bf16(
                    af[fr], *(bf16x8*)&bq[fc], acc[fr][fc], 0, 0, 0);
    }

    // ---- epilogue: bias + relu, per-row partial sums
    float bias_c[4], gam_c[4], bet_c[4];
    #pragma unroll
    for (int fc = 0; fc < 4; fc++) {
        int col = w * 64 + fc * 16 + l15;
        bias_c[fc] = bias[col];
        gam_c[fc]  = gamma[col];
        bet_c[fc]  = beta[col];
    }

    #pragma unroll
    for (int fr = 0; fr < 4; fr++) {
        #pragma unroll
        for (int r = 0; r < 4; r++) {
            int row = fr * 16 + l4 * 4 + r;
            float s = 0.f, q = 0.f;
            #pragma unroll
            for (int fc = 0; fc < 4; fc++) {
                float v = acc[fr][fc][r] + bias_c[fc];
                v = fmaxf(v, 0.f);
                acc[fr][fc][r] = v;
                s += v;
                q += v * v;
            }
            #pragma unroll
            for (int m = 1; m < 16; m <<= 1) {
                s += __shfl_xor(s, m);
                q += __shfl_xor(q, m);
            }
            if (l15 == 0) { red_s[row][w] = s; red_q[row][w] = q; }
        }
    }
    __syncthreads();   // red ready; all MFMA ds_reads done -> As reusable as f32 stage

    float* AsF = (float*)&As[0][0];   // [32][LDAF] f32 view, 33280 B <= 33792 B
    for (int h = 0; h < 2; ++h) {
        #pragma unroll
        for (int fr2 = 0; fr2 < 2; ++fr2) {
            int fr = h * 2 + fr2;
            #pragma unroll
            for (int r = 0; r < 4; ++r) {
                int row = fr * 16 + l4 * 4 + r;
                float s = red_s[row][0] + red_s[row][1] + red_s[row][2] + red_s[row][3];
                float q = red_q[row][0] + red_q[row][1] + red_q[row][2] + red_q[row][3];
                float mu  = s * (1.0f / 256.0f);
                float var = q * (1.0f / 256.0f) - mu * mu;
                float rstd = rsqrtf(var + 1e-5f);
                int lr = row - h * 32;
                #pragma unroll
                for (int fc = 0; fc < 4; ++fc) {
                    int col = w * 64 + fc * 16 + l15;
                    AsF[lr * LDAF + col] = (acc[fr][fc][r] - mu) * rstd * gam_c[fc] + bet_c[fc];
                }
            }
        }
        __syncthreads();
        #pragma unroll
        for (int j = 0; j < 8; ++j) {
            int r = j * 4 + w;
            int grow = row0 + h * 32 + r;
            if (grow < N) {
                float4 v = *(float4*)&AsF[r * LDAF + lane * 4];
                *(float4*)&Y[(size_t)grow * D + lane * 4] = v;
            }
        }
        __syncthreads();
    }
}

// ======================= FALLBACK PATH (R2, small-ws) =======================

__global__ void k_hist(const int* __restrict__ dst, int E, int* __restrict__ deg) {
    int e = blockIdx.x * blockDim.x + threadIdx.x;
    if (e < E) atomicAdd(&deg[dst[e]], 1);
}

__global__ void k_finalize_rs(int N, int* __restrict__ rs, const int* __restrict__ bsums) {
    int i = blockIdx.x * blockDim.x + threadIdx.x;
    if (i < N) rs[i + 1] += bsums[i >> 10];
    if (i == 0) rs[0] = 0;
}

__global__ void k_fill(const int* __restrict__ src, const int* __restrict__ dst, int E,
                       const int* __restrict__ rs, int* __restrict__ cursor,
                       int* __restrict__ csr) {
    int e = blockIdx.x * blockDim.x + threadIdx.x;
    if (e < E) {
        int d = dst[e];
        int p = atomicAdd(&cursor[d], 1);
        csr[rs[d] + p] = src[e];
    }
}

__global__ void k_msg_x(const float* __restrict__ srcf, const float* __restrict__ tgtf,
                        const int* __restrict__ rs, const int* __restrict__ csr,
                        int N, float* __restrict__ xout) {
    int wave = (blockIdx.x * blockDim.x + threadIdx.x) >> 6;
    int lane = threadIdx.x & 63;
    if (wave >= N) return;
    int s0 = rs[wave], s1 = rs[wave + 1];
    float4 acc = make_float4(0.f, 0.f, 0.f, 0.f);
    for (int i = s0; i < s1; i++) {
        int s = csr[i];
        float4 f = *(const float4*)&srcf[(size_t)s * D + lane * 4];
        acc.x += f.x; acc.y += f.y; acc.z += f.z; acc.w += f.w;
    }
    int cnt = s1 - s0;
    float inv = 1.0f / (float)(cnt > 0 ? cnt : 1);
    float4 t = *(const float4*)&tgtf[(size_t)wave * D + lane * 4];
    float4 x;
    x.x = t.x + acc.x * inv;
    x.y = t.y + acc.y * inv;
    x.z = t.z + acc.z * inv;
    x.w = t.w + acc.w * inv;
    *(float4*)&xout[(size_t)wave * D + lane * 4] = x;
}

__global__ void k_wcvt(const float* __restrict__ W0, const float* __restrict__ W1,
                       __hip_bfloat16* __restrict__ Wt0, __hip_bfloat16* __restrict__ Wt1) {
    int b = blockIdx.x;
    const float* W = (b < 256) ? W0 : W1;
    __hip_bfloat16* Wt = (b < 256) ? Wt0 : Wt1;
    int k = b & 255;
    int c = threadIdx.x;
    Wt[(size_t)c * 256 + k] = __float2bfloat16(W[(size_t)k * 256 + c]);
}

__launch_bounds__(256)
__global__ void k_gemm_mfma_ln(const float* __restrict__ X,
                               const __hip_bfloat16* __restrict__ Wt,
                               const float* __restrict__ bias,
                               const float* __restrict__ gamma,
                               const float* __restrict__ beta,
                               int N, float* __restrict__ Y) {
    __shared__ __hip_bfloat16 As[BM][LDK];
    __shared__ __hip_bfloat16 Bs[D][LDK];
    __shared__ float red_s[BM][4];
    __shared__ float red_q[BM][4];

    int t = threadIdx.x;
    int lane = t & 63;
    int w = t >> 6;
    int l15 = lane & 15;
    int l4 = lane >> 4;
    int row0 = blockIdx.x * BM;

    f32x4 acc[4][4];
    f32x4 zero = {0.f, 0.f, 0.f, 0.f};
    #pragma unroll
    for (int fr = 0; fr < 4; fr++)
        #pragma unroll
        for (int fc = 0; fc < 4; fc++)
            acc[fr][fc] = zero;

    for (int k0 = 0; k0 < D; k0 += 64) {
        {
            int i = t >> 2;
            int kq = (t & 3) * 16;
            int r = row0 + i;
            float4 f[4];
            if (r < N) {
                const float4* p = (const float4*)&X[(size_t)r * D + k0 + kq];
                f[0] = p[0]; f[1] = p[1]; f[2] = p[2]; f[3] = p[3];
            } else {
                float4 z4 = make_float4(0.f, 0.f, 0.f, 0.f);
                f[0] = z4; f[1] = z4; f[2] = z4; f[3] = z4;
            }
            __hip_bfloat16 vb[16];
            #pragma unroll
            for (int q = 0; q < 4; q++) {
                vb[q * 4 + 0] = __float2bfloat16(f[q].x);
                vb[q * 4 + 1] = __float2bfloat16(f[q].y);
                vb[q * 4 + 2] = __float2bfloat16(f[q].z);
                vb[q * 4 + 3] = __float2bfloat16(f[q].w);
            }
            *(uint4*)&As[i][kq]     = *(uint4*)&vb[0];
            *(uint4*)&As[i][kq + 8] = *(uint4*)&vb[8];
        }
        #pragma unroll
        for (int pass = 0; pass < 4; pass++) {
            int c = pass * 64 + (t >> 2);
            int kq = (t & 3) * 16;
            const uint4* p = (const uint4*)&Wt[(size_t)c * D + k0 + kq];
            uint4 b0 = p[0], b1 = p[1];
            *(uint4*)&Bs[c][kq]     = b0;
            *(uint4*)&Bs[c][kq + 8] = b1;
        }
        __syncthreads();

        #pragma unroll
        for (int ks = 0; ks < 2; ks++) {
            bf16x8 af[4], bg[4];
            #pragma unroll
            for (int fr = 0; fr < 4; fr++)
                af[fr] = *(const bf16x8*)&As[fr * 16 + l15][ks * 32 + l4 * 8];
            #pragma unroll
            for (int fc = 0; fc < 4; fc++)
                bg[fc] = *(const bf16x8*)&Bs[w * 64 + fc * 16 + l15][ks * 32 + l4 * 8];
            #pragma unroll
            for (int fr = 0; fr < 4; fr++)
                #pragma unroll
                for (int fc = 0; fc < 4; fc++)
                    acc[fr][fc] = __builtin_amdgcn_mfma_f32_16x16x32_bf16(
                        af[fr], bg[fc], acc[fr][fc], 0, 0, 0);
        }
        __syncthreads();
    }

    float bias_c[4], gam_c[4], bet_c[4];
    #pragma unroll
    for (int fc = 0; fc < 4; fc++) {
        int col = w * 64 + fc * 16 + l15;
        bias_c[fc] = bias[col];
        gam_c[fc]  = gamma[col];
        bet_c[fc]  = beta[col];
    }

    #pragma unroll
    for (int fr = 0; fr < 4; fr++) {
        #pragma unroll
        for (int r = 0; r < 4; r++) {
            int row = fr * 16 + l4 * 4 + r;
            float s = 0.f, q = 0.f;
            #pragma unroll
            for (int fc = 0; fc < 4; fc++) {
                float v = acc[fr][fc][r] + bias_c[fc];
                v = fmaxf(v, 0.f);
                acc[fr][fc][r] = v;
                s += v;
                q += v * v;
            }
            #pragma unroll
            for (int m = 1; m < 16; m <<= 1) {
                s += __shfl_xor(s, m);
                q += __shfl_xor(q, m);
            }
            if (l15 == 0) { red_s[row][w] = s; red_q[row][w] = q; }
        }
    }
    __syncthreads();

    #pragma unroll
    for (int fr = 0; fr < 4; fr++) {
        #pragma unroll
        for (int r = 0; r < 4; r++) {
            int row = fr * 16 + l4 * 4 + r;
            int grow = row0 + row;
            if (grow >= N) continue;
            float s = red_s[row][0] + red_s[row][1] + red_s[row][2] + red_s[row][3];
            float q = red_q[row][0] + red_q[row][1] + red_q[row][2] + red_q[row][3];
            float mu  = s * (1.0f / 256.0f);
            float var = q * (1.0f / 256.0f) - mu * mu;
            float rstd = rsqrtf(var + 1e-5f);
            #pragma unroll
            for (int fc = 0; fc < 4; fc++) {
                int col = w * 64 + fc * 16 + l15;
                Y[(size_t)grow * D + col] = (acc[fr][fc][r] - mu) * rstd * gam_c[fc] + bet_c[fc];
            }
        }
    }
}

// ======================= launch =======================

extern "C" void kernel_launch(void* const* d_in, const int* in_sizes, int n_in,
                              void* d_out, int out_size, void* d_ws, size_t ws_size,
                              hipStream_t stream) {
    const float* uf    = (const float*)d_in[0];
    const float* itf   = (const float*)d_in[1];
    const int*   ui_e  = (const int*)d_in[2];   // [2, Eui] user->item
    const int*   iu_e  = (const int*)d_in[3];   // [2, Eiu] item->user
    const float* Wu    = (const float*)d_in[4];
    const float* bu    = (const float*)d_in[5];
    const float* Wi    = (const float*)d_in[6];
    const float* bi    = (const float*)d_in[7];
    const float* gamma = (const float*)d_in[8];
    const float* beta  = (const float*)d_in[9];

    int NU  = in_sizes[0] / D;
    int NI  = in_sizes[1] / D;
    int Eui = in_sizes[2] / 2;
    int Eiu = in_sizes[3] / 2;
    int Nmax = NU > NI ? NU : NI;
    int Ntot = NU + NI;
    int Etot = Eiu + Eui;

    float* out   = (float*)d_out;
    size_t nfU = (size_t)NU * D;
    size_t nfI = (size_t)NI * D;
    size_t nfTot = nfU + nfI;

    // fast-path ws layout (no x buffers anymore)
    unsigned short* uf_bf = (unsigned short*)d_ws;     // nfU
    unsigned short* if_bf = uf_bf + nfU;               // nfI
    unsigned short* Wt_u2 = if_bf + nfI;               // 65536
    unsigned short* Wt_i2 = Wt_u2 + 65536;             // 65536
    int* deg2  = (int*)(Wt_i2 + 65536);                // Ntot
    int* rs2   = deg2 + Ntot;                          // Ntot+1
    int* cur2  = rs2 + Ntot + 1;                       // Ntot+1
    int* bsums = cur2 + Ntot + 1;                      // 1024
    int* csr2  = bsums + 1024;                         // Etot
    size_t needed = (size_t)((char*)(csr2 + Etot) - (char*)d_ws);

    if (ws_size >= needed) {
        int nbF = (int)((nfTot + 2047) / 2048);
        int nbH = (Etot + 255) / 256;
        hipMemsetAsync(deg2, 0, (size_t)Ntot * sizeof(int), stream);
        k_prep<<<nbF + 512 + nbH, 256, 0, stream>>>(uf, itf, Wu, Wi, uf_bf, Wt_u2, Wt_i2,
                                                    iu_e, Eiu, ui_e, Eui, deg2, NU,
                                                    nfU, nfTot, nbF);
        int nb = (Ntot + 1023) / 1024;
        k_scan_block<<<nb, 1024, 0, stream>>>(deg2, Ntot, rs2, bsums);
        k_scan_sums<<<1, 1024, 0, stream>>>(bsums, nb);
        k_finalize<<<(Ntot + 255) / 256, 256, 0, stream>>>(Ntot, rs2, cur2, bsums);
        k_fill2<<<nbH, 256, 0, stream>>>(iu_e, Eiu, ui_e, Eui, cur2, NU, csr2);
        int nbU = (NU + BM - 1) / BM;
        int nbI = (NI + BM - 1) / BM;
        k_fused<<<nbU + nbI, 256, 0, stream>>>(uf_bf, if_bf, Wt_u2, Wt_i2, rs2, csr2,
                                               bu, bi, gamma, beta, NU, NI, nbU, out);
        return;
    }

    // ---------- fallback: R2 path (needs ~2.2 MB ws) ----------
    float* u_out = out;
    float* i_out = out + nfU;
    __hip_bfloat16* Wt_u = (__hip_bfloat16*)d_ws;
    __hip_bfloat16* Wt_i = Wt_u + 256 * 256;
    int* deg    = (int*)(Wt_i + 256 * 256);
    int* rs     = deg + Nmax;
    int* bs     = rs + Nmax + 1;
    int* cursor = bs + 1024;
    int* csr    = cursor + Nmax;

    k_wcvt<<<512, 256, 0, stream>>>(Wu, Wi, Wt_u, Wt_i);

    auto run_side = [&](const float* srcf, const float* tgtf, const int* edges, int E,
                        int N, const __hip_bfloat16* Wt, const float* bias, float* y) {
        const int* esrc = edges;
        const int* edst = edges + E;
        hipMemsetAsync(deg, 0, (size_t)N * sizeof(int), stream);
        hipMemsetAsync(cursor, 0, (size_t)N * sizeof(int), stream);
        k_hist<<<(E + 255) / 256, 256, 0, stream>>>(edst, E, deg);
        int nb = (N + 1023) / 1024;
        k_scan_block<<<nb, 1024, 0, stream>>>(deg, N, rs, bs);
        k_scan_sums<<<1, 1024, 0, stream>>>(bs, nb);
        k_finalize_rs<<<(N + 255) / 256, 256, 0, stream>>>(N, rs, bs);
        k_fill<<<(E + 255) / 256, 256, 0, stream>>>(esrc, edst, E, rs, cursor, csr);
        k_msg_x<<<(N + 3) / 4, 256, 0, stream>>>(srcf, tgtf, rs, csr, N, y);
        k_gemm_mfma_ln<<<(N + BM - 1) / BM, 256, 0, stream>>>(y, Wt, bias, gamma, beta, N, y);
    };

    run_side(itf, uf, iu_e, Eiu, NU, Wt_u, bu, u_out);
    run_side(uf, itf, ui_e, Eui, NI, Wt_i, bi, i_out);
}

// Round 7
// 226.316 us; speedup vs baseline: 1.0646x; 1.0646x over previous
//
#include <hip/hip_runtime.h>
#include <hip/hip_bf16.h>

#define D 256
#define BM 64
#define LDA 264   // As k-stride in bf16 elems (528 B rows)
#define LDAF 260  // f32 restage stride (1040 B rows)
#define LDK 72    // fallback-path pad

typedef __attribute__((ext_vector_type(8))) __bf16 bf16x8;
typedef __attribute__((ext_vector_type(4))) float f32x4;

__device__ __forceinline__ float bf2f(unsigned short u) {
    union { unsigned int i; float f; } c; c.i = ((unsigned int)u) << 16; return c.f;
}
__device__ __forceinline__ float bf2f_lo(unsigned int u) {
    union { unsigned int i; float f; } c; c.i = u << 16; return c.f;
}
__device__ __forceinline__ float bf2f_hi(unsigned int u) {
    union { unsigned int i; float f; } c; c.i = u & 0xffff0000u; return c.f;
}
__device__ __forceinline__ unsigned short f2bf(float f) {
    __hip_bfloat16 h = __float2bfloat16(f);
    return *reinterpret_cast<unsigned short*>(&h);
}
__device__ __forceinline__ unsigned int pack2(float lo, float hi) {
    return (unsigned int)f2bf(lo) | ((unsigned int)f2bf(hi) << 16);
}

// ======================= FAST PATH =======================

// blocks [0,nbF): feat fp32->bf16 ; [nbF,nbF+512): W->Wt[c][k] ; rest: edge histogram.
// deg must be zeroed before this kernel.
__global__ void k_prep(const float* __restrict__ uf, const float* __restrict__ itf,
                       const float* __restrict__ Wu, const float* __restrict__ Wi,
                       unsigned short* __restrict__ feat_bf,
                       unsigned short* __restrict__ Wt_u, unsigned short* __restrict__ Wt_i,
                       const int* __restrict__ iu_e, int Eiu,
                       const int* __restrict__ ui_e, int Eui,
                       int* __restrict__ deg, int NU,
                       size_t nfU, size_t nfTot, int nbF) {
    int b = blockIdx.x;
    if (b < nbF) {
        size_t base = ((size_t)b * 256 + threadIdx.x) * 8;
        if (base < nfTot) {
            const float* s = (base < nfU) ? (uf + base) : (itf + (base - nfU));
            float4 f0 = *(const float4*)s;
            float4 f1 = *(const float4*)(s + 4);
            ushort4 o0, o1;
            o0.x = f2bf(f0.x); o0.y = f2bf(f0.y); o0.z = f2bf(f0.z); o0.w = f2bf(f0.w);
            o1.x = f2bf(f1.x); o1.y = f2bf(f1.y); o1.z = f2bf(f1.z); o1.w = f2bf(f1.w);
            ((ushort4*)(feat_bf + base))[0] = o0;
            ((ushort4*)(feat_bf + base))[1] = o1;
        }
    } else if (b < nbF + 512) {
        int b2 = b - nbF;
        const float* W = (b2 < 256) ? Wu : Wi;
        unsigned short* Wt = (b2 < 256) ? Wt_u : Wt_i;
        int k = b2 & 255;
        int c = threadIdx.x;
        Wt[(size_t)c * 256 + k] = f2bf(W[(size_t)k * 256 + c]);
    } else {
        int e = (b - nbF - 512) * 256 + threadIdx.x;
        if (e < Eiu) {
            atomicAdd(&deg[iu_e[Eiu + e]], 1);
        } else if (e < Eiu + Eui) {
            int e2 = e - Eiu;
            atomicAdd(&deg[NU + ui_e[Eui + e2]], 1);
        }
    }
}

__global__ void k_scan_block(const int* __restrict__ deg, int N,
                             int* __restrict__ rs, int* __restrict__ bsums) {
    __shared__ int s[1024];
    int base = blockIdx.x * 1024;
    int t = threadIdx.x;
    int v = (base + t < N) ? deg[base + t] : 0;
    s[t] = v;
    __syncthreads();
    for (int off = 1; off < 1024; off <<= 1) {
        int add = (t >= off) ? s[t - off] : 0;
        __syncthreads();
        s[t] += add;
        __syncthreads();
    }
    if (base + t < N) rs[base + t + 1] = s[t];
    if (t == 1023) bsums[blockIdx.x] = s[1023];
}

__global__ void k_scan_sums(int* __restrict__ bsums, int nb) {
    __shared__ int s[1024];
    int t = threadIdx.x;
    int v = (t < nb) ? bsums[t] : 0;
    s[t] = v;
    __syncthreads();
    for (int off = 1; off < 1024; off <<= 1) {
        int add = (t >= off) ? s[t - off] : 0;
        __syncthreads();
        s[t] += add;
        __syncthreads();
    }
    if (t < nb) bsums[t] = s[t] - v;
}

__global__ void k_finalize(int N, int* __restrict__ rs, int* __restrict__ cur,
                           const int* __restrict__ bsums) {
    int i = blockIdx.x * blockDim.x + threadIdx.x;
    if (i < N) {
        int v = rs[i + 1] + bsums[i >> 10];
        rs[i + 1] = v;
        cur[i + 1] = v;
    }
    if (i == 0) { rs[0] = 0; cur[0] = 0; }
}

__global__ void k_fill2(const int* __restrict__ iu_e, int Eiu,
                        const int* __restrict__ ui_e, int Eui,
                        int* __restrict__ cur, int NU,
                        int* __restrict__ csr) {
    int e = blockIdx.x * blockDim.x + threadIdx.x;
    if (e < Eiu) {
        int d = iu_e[Eiu + e];
        int p = atomicAdd(&cur[d], 1);
        csr[p] = iu_e[e];
    } else if (e < Eiu + Eui) {
        int e2 = e - Eiu;
        int d = ui_e[Eui + e2];
        int p = atomicAdd(&cur[NU + d], 1);
        csr[p] = ui_e[e2];
    }
}

// x = bf16( tgt + mean(src rows) ); TWO rows per wave (half-wave each),
// 4-unrolled gather -> up to 8 independent row loads in flight. High-occupancy.
__global__ void k_msg2(const unsigned short* __restrict__ uf_bf,
                       const unsigned short* __restrict__ if_bf,
                       const int* __restrict__ rs, const int* __restrict__ csr,
                       unsigned short* __restrict__ x_u, unsigned short* __restrict__ x_i,
                       int NU, int NI) {
    int pair = (blockIdx.x * blockDim.x + threadIdx.x) >> 6;
    int lane = threadIdx.x & 63;
    int half = lane >> 5;
    int hl   = lane & 31;
    int Ntot = NU + NI;
    int wv = pair * 2 + half;
    if (wv >= Ntot) return;

    const unsigned short* src; const unsigned short* tgt; unsigned short* xo; int w;
    if (wv < NU) { src = if_bf; tgt = uf_bf; xo = x_u; w = wv; }
    else         { src = uf_bf; tgt = if_bf; xo = x_i; w = wv - NU; }

    int s0 = rs[wv], s1 = rs[wv + 1];
    float a0[8] = {}, a1[8] = {}, a2[8] = {}, a3[8] = {};

    int i = s0;
    for (; i + 4 <= s1; i += 4) {
        int e0 = csr[i], e1 = csr[i + 1], e2 = csr[i + 2], e3 = csr[i + 3];
        uint4 r0 = ((const uint4*)(src + (size_t)e0 * D))[hl];
        uint4 r1 = ((const uint4*)(src + (size_t)e1 * D))[hl];
        uint4 r2 = ((const uint4*)(src + (size_t)e2 * D))[hl];
        uint4 r3 = ((const uint4*)(src + (size_t)e3 * D))[hl];
        a0[0] += bf2f_lo(r0.x); a0[1] += bf2f_hi(r0.x); a0[2] += bf2f_lo(r0.y); a0[3] += bf2f_hi(r0.y);
        a0[4] += bf2f_lo(r0.z); a0[5] += bf2f_hi(r0.z); a0[6] += bf2f_lo(r0.w); a0[7] += bf2f_hi(r0.w);
        a1[0] += bf2f_lo(r1.x); a1[1] += bf2f_hi(r1.x); a1[2] += bf2f_lo(r1.y); a1[3] += bf2f_hi(r1.y);
        a1[4] += bf2f_lo(r1.z); a1[5] += bf2f_hi(r1.z); a1[6] += bf2f_lo(r1.w); a1[7] += bf2f_hi(r1.w);
        a2[0] += bf2f_lo(r2.x); a2[1] += bf2f_hi(r2.x); a2[2] += bf2f_lo(r2.y); a2[3] += bf2f_hi(r2.y);
        a2[4] += bf2f_lo(r2.z); a2[5] += bf2f_hi(r2.z); a2[6] += bf2f_lo(r2.w); a2[7] += bf2f_hi(r2.w);
        a3[0] += bf2f_lo(r3.x); a3[1] += bf2f_hi(r3.x); a3[2] += bf2f_lo(r3.y); a3[3] += bf2f_hi(r3.y);
        a3[4] += bf2f_lo(r3.z); a3[5] += bf2f_hi(r3.z); a3[6] += bf2f_lo(r3.w); a3[7] += bf2f_hi(r3.w);
    }
    for (; i < s1; ++i) {
        int e0 = csr[i];
        uint4 r0 = ((const uint4*)(src + (size_t)e0 * D))[hl];
        a0[0] += bf2f_lo(r0.x); a0[1] += bf2f_hi(r0.x); a0[2] += bf2f_lo(r0.y); a0[3] += bf2f_hi(r0.y);
        a0[4] += bf2f_lo(r0.z); a0[5] += bf2f_hi(r0.z); a0[6] += bf2f_lo(r0.w); a0[7] += bf2f_hi(r0.w);
    }

    int cnt = s1 - s0;
    float inv = 1.0f / (float)(cnt > 0 ? cnt : 1);
    uint4 tv = ((const uint4*)(tgt + (size_t)w * D))[hl];
    float x0 = bf2f_lo(tv.x) + (a0[0] + a1[0] + a2[0] + a3[0]) * inv;
    float x1 = bf2f_hi(tv.x) + (a0[1] + a1[1] + a2[1] + a3[1]) * inv;
    float x2 = bf2f_lo(tv.y) + (a0[2] + a1[2] + a2[2] + a3[2]) * inv;
    float x3 = bf2f_hi(tv.y) + (a0[3] + a1[3] + a2[3] + a3[3]) * inv;
    float x4 = bf2f_lo(tv.z) + (a0[4] + a1[4] + a2[4] + a3[4]) * inv;
    float x5 = bf2f_hi(tv.z) + (a0[5] + a1[5] + a2[5] + a3[5]) * inv;
    float x6 = bf2f_lo(tv.w) + (a0[6] + a1[6] + a2[6] + a3[6]) * inv;
    float x7 = bf2f_hi(tv.w) + (a0[7] + a1[7] + a2[7] + a3[7]) * inv;
    uint4 o;
    o.x = pack2(x0, x1); o.y = pack2(x2, x3); o.z = pack2(x4, x5); o.w = pack2(x6, x7);
    ((uint4*)(xo + (size_t)w * D))[hl] = o;
}

// ---- GEMM + bias + ReLU + LayerNorm. A staged once (coalesced), ONE barrier,
//      B fragments streamed directly from L2 (no Bs, no K-loop barriers),
//      epilogue restaged through LDS for full-line float4 stores.
__launch_bounds__(256)
__global__ void k_gemm3(const unsigned short* __restrict__ x_u,
                        const unsigned short* __restrict__ x_i,
                        const unsigned short* __restrict__ Wt_u,
                        const unsigned short* __restrict__ Wt_i,
                        const float* __restrict__ bu, const float* __restrict__ bi,
                        const float* __restrict__ gamma, const float* __restrict__ beta,
                        int NU, int NI, int nbU, float* __restrict__ out) {
    __shared__ __align__(16) __hip_bfloat16 As[BM][LDA];   // 33792 B
    __shared__ float red_s[BM][4];
    __shared__ float red_q[BM][4];

    int b = blockIdx.x;
    bool isU = b < nbU;
    const unsigned short* X  = isU ? x_u : x_i;
    const unsigned short* Wt = isU ? Wt_u : Wt_i;
    const float* bias        = isU ? bu : bi;
    float* Y                 = isU ? out : out + (size_t)NU * D;
    int N                    = isU ? NU : NI;
    int row0 = (isU ? b : b - nbU) * BM;

    int t = threadIdx.x;
    int lane = t & 63;
    int w = t >> 6;
    int l15 = lane & 15;
    int l4 = lane >> 4;

    // ---- stage A once: 8 x 4KB fully-coalesced loads
    {
        const uint4* Xg = (const uint4*)&X[(size_t)row0 * D];
        #pragma unroll
        for (int j = 0; j < 8; ++j) {
            int lr = (t >> 5) + j * 8;
            uint4 v = {0, 0, 0, 0};
            if (row0 + lr < N) v = Xg[(size_t)lr * 32 + (t & 31)];
            *(uint4*)&As[lr][(t & 31) * 8] = v;
        }
    }

    f32x4 acc[4][4];
    f32x4 zero = {0.f, 0.f, 0.f, 0.f};
    #pragma unroll
    for (int fr = 0; fr < 4; fr++)
        #pragma unroll
        for (int fc = 0; fc < 4; fc++)
            acc[fr][fc] = zero;

    __syncthreads();

    // ---- GEMM: A from LDS, B straight from L2; no barriers in the loop.
    const uint4* Bg = (const uint4*)Wt;   // Wt[col][k]: uint4 index = col*32 + k/8
    int colB = w * 64 + l15;
    #pragma unroll
    for (int ks8 = 0; ks8 < 8; ++ks8) {
        uint4 bq[4];
        #pragma unroll
        for (int fc = 0; fc < 4; ++fc)
            bq[fc] = Bg[(size_t)(colB + fc * 16) * 32 + ks8 * 4 + l4];
        bf16x8 af[4];
        #pragma unroll
        for (int fr = 0; fr < 4; ++fr)
            af[fr] = *(const bf16x8*)&As[fr * 16 + l15][ks8 * 32 + l4 * 8];
        #pragma unroll
        for (int fr = 0; fr < 4; ++fr)
            #pragma unroll
            for (int fc = 0; fc < 4; ++fc)
                acc[fr][fc] = __builtin_amdgcn_mfma_f32_16x16x32_bf16(
                    af[fr], *(bf16x8*)&bq[fc], acc[fr][fc], 0, 0, 0);
    }

    // ---- epilogue: bias + relu + per-row reduce
    float bias_c[4], gam_c[4], bet_c[4];
    #pragma unroll
    for (int fc = 0; fc < 4; fc++) {
        int col = w * 64 + fc * 16 + l15;
        bias_c[fc] = bias[col];
        gam_c[fc]  = gamma[col];
        bet_c[fc]  = beta[col];
    }

    #pragma unroll
    for (int fr = 0; fr < 4; fr++) {
        #pragma unroll
        for (int r = 0; r < 4; r++) {
            int row = fr * 16 + l4 * 4 + r;
            float s = 0.f, q = 0.f;
            #pragma unroll
            for (int fc = 0; fc < 4; fc++) {
                float v = acc[fr][fc][r] + bias_c[fc];
                v = fmaxf(v, 0.f);
                acc[fr][fc][r] = v;
                s += v;
                q += v * v;
            }
            #pragma unroll
            for (int m = 1; m < 16; m <<= 1) {
                s += __shfl_xor(s, m);
                q += __shfl_xor(q, m);
            }
            if (l15 == 0) { red_s[row][w] = s; red_q[row][w] = q; }
        }
    }
    __syncthreads();   // red ready; MFMA ds_reads done -> As reusable as f32 stage

    float* AsF = (float*)&As[0][0];   // [32][LDAF] f32 view, 33280 B <= 33792 B
    for (int h = 0; h < 2; ++h) {
        #pragma unroll
        for (int fr2 = 0; fr2 < 2; ++fr2) {
            int fr = h * 2 + fr2;
            #pragma unroll
            for (int r = 0; r < 4; ++r) {
                int row = fr * 16 + l4 * 4 + r;
                float s = red_s[row][0] + red_s[row][1] + red_s[row][2] + red_s[row][3];
                float q = red_q[row][0] + red_q[row][1] + red_q[row][2] + red_q[row][3];
                float mu  = s * (1.0f / 256.0f);
                float var = q * (1.0f / 256.0f) - mu * mu;
                float rstd = rsqrtf(var + 1e-5f);
                int lr = row - h * 32;
                #pragma unroll
                for (int fc = 0; fc < 4; ++fc) {
                    int col = w * 64 + fc * 16 + l15;
                    AsF[lr * LDAF + col] = (acc[fr][fc][r] - mu) * rstd * gam_c[fc] + bet_c[fc];
                }
            }
        }
        __syncthreads();
        #pragma unroll
        for (int j = 0; j < 8; ++j) {
            int r = j * 4 + w;
            int grow = row0 + h * 32 + r;
            if (grow < N) {
                float4 v = *(float4*)&AsF[r * LDAF + lane * 4];
                *(float4*)&Y[(size_t)grow * D + lane * 4] = v;
            }
        }
        __syncthreads();
    }
}

// ======================= FALLBACK PATH (R2, small-ws) =======================

__global__ void k_hist(const int* __restrict__ dst, int E, int* __restrict__ deg) {
    int e = blockIdx.x * blockDim.x + threadIdx.x;
    if (e < E) atomicAdd(&deg[dst[e]], 1);
}

__global__ void k_finalize_rs(int N, int* __restrict__ rs, const int* __restrict__ bsums) {
    int i = blockIdx.x * blockDim.x + threadIdx.x;
    if (i < N) rs[i + 1] += bsums[i >> 10];
    if (i == 0) rs[0] = 0;
}

__global__ void k_fill(const int* __restrict__ src, const int* __restrict__ dst, int E,
                       const int* __restrict__ rs, int* __restrict__ cursor,
                       int* __restrict__ csr) {
    int e = blockIdx.x * blockDim.x + threadIdx.x;
    if (e < E) {
        int d = dst[e];
        int p = atomicAdd(&cursor[d], 1);
        csr[rs[d] + p] = src[e];
    }
}

__global__ void k_msg_x(const float* __restrict__ srcf, const float* __restrict__ tgtf,
                        const int* __restrict__ rs, const int* __restrict__ csr,
                        int N, float* __restrict__ xout) {
    int wave = (blockIdx.x * blockDim.x + threadIdx.x) >> 6;
    int lane = threadIdx.x & 63;
    if (wave >= N) return;
    int s0 = rs[wave], s1 = rs[wave + 1];
    float4 acc = make_float4(0.f, 0.f, 0.f, 0.f);
    for (int i = s0; i < s1; i++) {
        int s = csr[i];
        float4 f = *(const float4*)&srcf[(size_t)s * D + lane * 4];
        acc.x += f.x; acc.y += f.y; acc.z += f.z; acc.w += f.w;
    }
    int cnt = s1 - s0;
    float inv = 1.0f / (float)(cnt > 0 ? cnt : 1);
    float4 t = *(const float4*)&tgtf[(size_t)wave * D + lane * 4];
    float4 x;
    x.x = t.x + acc.x * inv;
    x.y = t.y + acc.y * inv;
    x.z = t.z + acc.z * inv;
    x.w = t.w + acc.w * inv;
    *(float4*)&xout[(size_t)wave * D + lane * 4] = x;
}

__global__ void k_wcvt(const float* __restrict__ W0, const float* __restrict__ W1,
                       __hip_bfloat16* __restrict__ Wt0, __hip_bfloat16* __restrict__ Wt1) {
    int b = blockIdx.x;
    const float* W = (b < 256) ? W0 : W1;
    __hip_bfloat16* Wt = (b < 256) ? Wt0 : Wt1;
    int k = b & 255;
    int c = threadIdx.x;
    Wt[(size_t)c * 256 + k] = __float2bfloat16(W[(size_t)k * 256 + c]);
}

__launch_bounds__(256)
__global__ void k_gemm_mfma_ln(const float* __restrict__ X,
                               const __hip_bfloat16* __restrict__ Wt,
                               const float* __restrict__ bias,
                               const float* __restrict__ gamma,
                               const float* __restrict__ beta,
                               int N, float* __restrict__ Y) {
    __shared__ __hip_bfloat16 As[BM][LDK];
    __shared__ __hip_bfloat16 Bs[D][LDK];
    __shared__ float red_s[BM][4];
    __shared__ float red_q[BM][4];

    int t = threadIdx.x;
    int lane = t & 63;
    int w = t >> 6;
    int l15 = lane & 15;
    int l4 = lane >> 4;
    int row0 = blockIdx.x * BM;

    f32x4 acc[4][4];
    f32x4 zero = {0.f, 0.f, 0.f, 0.f};
    #pragma unroll
    for (int fr = 0; fr < 4; fr++)
        #pragma unroll
        for (int fc = 0; fc < 4; fc++)
            acc[fr][fc] = zero;

    for (int k0 = 0; k0 < D; k0 += 64) {
        {
            int i = t >> 2;
            int kq = (t & 3) * 16;
            int r = row0 + i;
            float4 f[4];
            if (r < N) {
                const float4* p = (const float4*)&X[(size_t)r * D + k0 + kq];
                f[0] = p[0]; f[1] = p[1]; f[2] = p[2]; f[3] = p[3];
            } else {
                float4 z4 = make_float4(0.f, 0.f, 0.f, 0.f);
                f[0] = z4; f[1] = z4; f[2] = z4; f[3] = z4;
            }
            __hip_bfloat16 vb[16];
            #pragma unroll
            for (int q = 0; q < 4; q++) {
                vb[q * 4 + 0] = __float2bfloat16(f[q].x);
                vb[q * 4 + 1] = __float2bfloat16(f[q].y);
                vb[q * 4 + 2] = __float2bfloat16(f[q].z);
                vb[q * 4 + 3] = __float2bfloat16(f[q].w);
            }
            *(uint4*)&As[i][kq]     = *(uint4*)&vb[0];
            *(uint4*)&As[i][kq + 8] = *(uint4*)&vb[8];
        }
        #pragma unroll
        for (int pass = 0; pass < 4; pass++) {
            int c = pass * 64 + (t >> 2);
            int kq = (t & 3) * 16;
            const uint4* p = (const uint4*)&Wt[(size_t)c * D + k0 + kq];
            uint4 b0 = p[0], b1 = p[1];
            *(uint4*)&Bs[c][kq]     = b0;
            *(uint4*)&Bs[c][kq + 8] = b1;
        }
        __syncthreads();

        #pragma unroll
        for (int ks = 0; ks < 2; ks++) {
            bf16x8 af[4], bg[4];
            #pragma unroll
            for (int fr = 0; fr < 4; fr++)
                af[fr] = *(const bf16x8*)&As[fr * 16 + l15][ks * 32 + l4 * 8];
            #pragma unroll
            for (int fc = 0; fc < 4; fc++)
                bg[fc] = *(const bf16x8*)&Bs[w * 64 + fc * 16 + l15][ks * 32 + l4 * 8];
            #pragma unroll
            for (int fr = 0; fr < 4; fr++)
                #pragma unroll
                for (int fc = 0; fc < 4; fc++)
                    acc[fr][fc] = __builtin_amdgcn_mfma_f32_16x16x32_bf16(
                        af[fr], bg[fc], acc[fr][fc], 0, 0, 0);
        }
        __syncthreads();
    }

    float bias_c[4], gam_c[4], bet_c[4];
    #pragma unroll
    for (int fc = 0; fc < 4; fc++) {
        int col = w * 64 + fc * 16 + l15;
        bias_c[fc] = bias[col];
        gam_c[fc]  = gamma[col];
        bet_c[fc]  = beta[col];
    }

    #pragma unroll
    for (int fr = 0; fr < 4; fr++) {
        #pragma unroll
        for (int r = 0; r < 4; r++) {
            int row = fr * 16 + l4 * 4 + r;
            float s = 0.f, q = 0.f;
            #pragma unroll
            for (int fc = 0; fc < 4; fc++) {
                float v = acc[fr][fc][r] + bias_c[fc];
                v = fmaxf(v, 0.f);
                acc[fr][fc][r] = v;
                s += v;
                q += v * v;
            }
            #pragma unroll
            for (int m = 1; m < 16; m <<= 1) {
                s += __shfl_xor(s, m);
                q += __shfl_xor(q, m);
            }
            if (l15 == 0) { red_s[row][w] = s; red_q[row][w] = q; }
        }
    }
    __syncthreads();

    #pragma unroll
    for (int fr = 0; fr < 4; fr++) {
        #pragma unroll
        for (int r = 0; r < 4; r++) {
            int row = fr * 16 + l4 * 4 + r;
            int grow = row0 + row;
            if (grow >= N) continue;
            float s = red_s[row][0] + red_s[row][1] + red_s[row][2] + red_s[row][3];
            float q = red_q[row][0] + red_q[row][1] + red_q[row][2] + red_q[row][3];
            float mu  = s * (1.0f / 256.0f);
            float var = q * (1.0f / 256.0f) - mu * mu;
            float rstd = rsqrtf(var + 1e-5f);
            #pragma unroll
            for (int fc = 0; fc < 4; fc++) {
                int col = w * 64 + fc * 16 + l15;
                Y[(size_t)grow * D + col] = (acc[fr][fc][r] - mu) * rstd * gam_c[fc] + bet_c[fc];
            }
        }
    }
}

// ======================= launch =======================

extern "C" void kernel_launch(void* const* d_in, const int* in_sizes, int n_in,
                              void* d_out, int out_size, void* d_ws, size_t ws_size,
                              hipStream_t stream) {
    const float* uf    = (const float*)d_in[0];
    const float* itf   = (const float*)d_in[1];
    const int*   ui_e  = (const int*)d_in[2];   // [2, Eui] user->item
    const int*   iu_e  = (const int*)d_in[3];   // [2, Eiu] item->user
    const float* Wu    = (const float*)d_in[4];
    const float* bu    = (const float*)d_in[5];
    const float* Wi    = (const float*)d_in[6];
    const float* bi    = (const float*)d_in[7];
    const float* gamma = (const float*)d_in[8];
    const float* beta  = (const float*)d_in[9];

    int NU  = in_sizes[0] / D;
    int NI  = in_sizes[1] / D;
    int Eui = in_sizes[2] / 2;
    int Eiu = in_sizes[3] / 2;
    int Nmax = NU > NI ? NU : NI;
    int Ntot = NU + NI;
    int Etot = Eiu + Eui;

    float* out   = (float*)d_out;
    size_t nfU = (size_t)NU * D;
    size_t nfI = (size_t)NI * D;
    size_t nfTot = nfU + nfI;

    // fast-path ws layout
    unsigned short* uf_bf = (unsigned short*)d_ws;     // nfU
    unsigned short* if_bf = uf_bf + nfU;               // nfI
    unsigned short* x_u   = if_bf + nfI;               // nfU
    unsigned short* x_i   = x_u + nfU;                 // nfI
    unsigned short* Wt_u2 = x_i + nfI;                 // 65536
    unsigned short* Wt_i2 = Wt_u2 + 65536;             // 65536
    int* deg2  = (int*)(Wt_i2 + 65536);                // Ntot
    int* rs2   = deg2 + Ntot;                          // Ntot+1
    int* cur2  = rs2 + Ntot + 1;                       // Ntot+1
    int* bsums = cur2 + Ntot + 1;                      // 1024
    int* csr2  = bsums + 1024;                         // Etot
    size_t needed = (size_t)((char*)(csr2 + Etot) - (char*)d_ws);

    if (ws_size >= needed) {
        int nbF = (int)((nfTot + 2047) / 2048);
        int nbH = (Etot + 255) / 256;
        hipMemsetAsync(deg2, 0, (size_t)Ntot * sizeof(int), stream);
        k_prep<<<nbF + 512 + nbH, 256, 0, stream>>>(uf, itf, Wu, Wi, uf_bf, Wt_u2, Wt_i2,
                                                    iu_e, Eiu, ui_e, Eui, deg2, NU,
                                                    nfU, nfTot, nbF);
        int nb = (Ntot + 1023) / 1024;
        k_scan_block<<<nb, 1024, 0, stream>>>(deg2, Ntot, rs2, bsums);
        k_scan_sums<<<1, 1024, 0, stream>>>(bsums, nb);
        k_finalize<<<(Ntot + 255) / 256, 256, 0, stream>>>(Ntot, rs2, cur2, bsums);
        k_fill2<<<nbH, 256, 0, stream>>>(iu_e, Eiu, ui_e, Eui, cur2, NU, csr2);
        int pairs = (Ntot + 1) / 2;
        k_msg2<<<(pairs + 3) / 4, 256, 0, stream>>>(uf_bf, if_bf, rs2, csr2, x_u, x_i, NU, NI);
        int nbU = (NU + BM - 1) / BM;
        int nbI = (NI + BM - 1) / BM;
        k_gemm3<<<nbU + nbI, 256, 0, stream>>>(x_u, x_i, Wt_u2, Wt_i2, bu, bi, gamma, beta,
                                               NU, NI, nbU, out);
        return;
    }

    // ---------- fallback: R2 path (needs ~2.2 MB ws) ----------
    float* u_out = out;
    float* i_out = out + nfU;
    __hip_bfloat16* Wt_u = (__hip_bfloat16*)d_ws;
    __hip_bfloat16* Wt_i = Wt_u + 256 * 256;
    int* deg    = (int*)(Wt_i + 256 * 256);
    int* rs     = deg + Nmax;
    int* bs     = rs + Nmax + 1;
    int* cursor = bs + 1024;
    int* csr    = cursor + Nmax;

    k_wcvt<<<512, 256, 0, stream>>>(Wu, Wi, Wt_u, Wt_i);

    auto run_side = [&](const float* srcf, const float* tgtf, const int* edges, int E,
                        int N, const __hip_bfloat16* Wt, const float* bias, float* y) {
        const int* esrc = edges;
        const int* edst = edges + E;
        hipMemsetAsync(deg, 0, (size_t)N * sizeof(int), stream);
        hipMemsetAsync(cursor, 0, (size_t)N * sizeof(int), stream);
        k_hist<<<(E + 255) / 256, 256, 0, stream>>>(edst, E, deg);
        int nb = (N + 1023) / 1024;
        k_scan_block<<<nb, 1024, 0, stream>>>(deg, N, rs, bs);
        k_scan_sums<<<1, 1024, 0, stream>>>(bs, nb);
        k_finalize_rs<<<(N + 255) / 256, 256, 0, stream>>>(N, rs, bs);
        k_fill<<<(E + 255) / 256, 256, 0, stream>>>(esrc, edst, E, rs, cursor, csr);
        k_msg_x<<<(N + 3) / 4, 256, 0, stream>>>(srcf, tgtf, rs, csr, N, y);
        k_gemm_mfma_ln<<<(N + BM - 1) / BM, 256, 0, stream>>>(y, Wt, bias, gamma, beta, N, y);
    };

    run_side(itf, uf, iu_e, Eiu, NU, Wt_u, bu, u_out);
    run_side(uf, itf, ui_e, Eui, NI, Wt_i, bi, i_out);
}

// Round 9
// 218.410 us; speedup vs baseline: 1.1031x; 1.0362x over previous
//
#include <hip/hip_runtime.h>
#include <hip/hip_bf16.h>

#define D 256
#define BM 64
#define BM2 32    // gemm5 tile rows
#define LDA 264   // LDS k-stride in bf16 elems (528 B rows)
#define LDK 72    // fallback-path pad

typedef __attribute__((ext_vector_type(8))) __bf16 bf16x8;
typedef __attribute__((ext_vector_type(4))) float f32x4;

__device__ __forceinline__ float bf2f(unsigned short u) {
    union { unsigned int i; float f; } c; c.i = ((unsigned int)u) << 16; return c.f;
}
__device__ __forceinline__ float bf2f_lo(unsigned int u) {
    union { unsigned int i; float f; } c; c.i = u << 16; return c.f;
}
__device__ __forceinline__ float bf2f_hi(unsigned int u) {
    union { unsigned int i; float f; } c; c.i = u & 0xffff0000u; return c.f;
}
__device__ __forceinline__ unsigned short f2bf(float f) {
    __hip_bfloat16 h = __float2bfloat16(f);
    return *reinterpret_cast<unsigned short*>(&h);
}
__device__ __forceinline__ unsigned int pack2(float lo, float hi) {
    return (unsigned int)f2bf(lo) | ((unsigned int)f2bf(hi) << 16);
}

// ======================= FAST PATH =======================

// blocks [0,nbF): feat fp32->bf16 ; [nbF,nbF+512): W->Wt[c][k] ; rest: edge histogram.
// deg must be zeroed before this kernel.
__global__ void k_prep(const float* __restrict__ uf, const float* __restrict__ itf,
                       const float* __restrict__ Wu, const float* __restrict__ Wi,
                       unsigned short* __restrict__ feat_bf,
                       unsigned short* __restrict__ Wt_u, unsigned short* __restrict__ Wt_i,
                       const int* __restrict__ iu_e, int Eiu,
                       const int* __restrict__ ui_e, int Eui,
                       int* __restrict__ deg, int NU,
                       size_t nfU, size_t nfTot, int nbF) {
    int b = blockIdx.x;
    if (b < nbF) {
        size_t base = ((size_t)b * 256 + threadIdx.x) * 8;
        if (base < nfTot) {
            const float* s = (base < nfU) ? (uf + base) : (itf + (base - nfU));
            float4 f0 = *(const float4*)s;
            float4 f1 = *(const float4*)(s + 4);
            ushort4 o0, o1;
            o0.x = f2bf(f0.x); o0.y = f2bf(f0.y); o0.z = f2bf(f0.z); o0.w = f2bf(f0.w);
            o1.x = f2bf(f1.x); o1.y = f2bf(f1.y); o1.z = f2bf(f1.z); o1.w = f2bf(f1.w);
            ((ushort4*)(feat_bf + base))[0] = o0;
            ((ushort4*)(feat_bf + base))[1] = o1;
        }
    } else if (b < nbF + 512) {
        int b2 = b - nbF;
        const float* W = (b2 < 256) ? Wu : Wi;
        unsigned short* Wt = (b2 < 256) ? Wt_u : Wt_i;
        int k = b2 & 255;
        int c = threadIdx.x;
        Wt[(size_t)c * 256 + k] = f2bf(W[(size_t)k * 256 + c]);
    } else {
        int e = (b - nbF - 512) * 256 + threadIdx.x;
        if (e < Eiu) {
            atomicAdd(&deg[iu_e[Eiu + e]], 1);
        } else if (e < Eiu + Eui) {
            int e2 = e - Eiu;
            atomicAdd(&deg[NU + ui_e[Eui + e2]], 1);
        }
    }
}

__global__ void k_scan_block(const int* __restrict__ deg, int N,
                             int* __restrict__ rs, int* __restrict__ bsums) {
    __shared__ int s[1024];
    int base = blockIdx.x * 1024;
    int t = threadIdx.x;
    int v = (base + t < N) ? deg[base + t] : 0;
    s[t] = v;
    __syncthreads();
    for (int off = 1; off < 1024; off <<= 1) {
        int add = (t >= off) ? s[t - off] : 0;
        __syncthreads();
        s[t] += add;
        __syncthreads();
    }
    if (base + t < N) rs[base + t + 1] = s[t];
    if (t == 1023) bsums[blockIdx.x] = s[1023];
}

__global__ void k_scan_sums(int* __restrict__ bsums, int nb) {
    __shared__ int s[1024];
    int t = threadIdx.x;
    int v = (t < nb) ? bsums[t] : 0;
    s[t] = v;
    __syncthreads();
    for (int off = 1; off < 1024; off <<= 1) {
        int add = (t >= off) ? s[t - off] : 0;
        __syncthreads();
        s[t] += add;
        __syncthreads();
    }
    if (t < nb) bsums[t] = s[t] - v;
}

__global__ void k_finalize(int N, int* __restrict__ rs, int* __restrict__ cur,
                           const int* __restrict__ bsums) {
    int i = blockIdx.x * blockDim.x + threadIdx.x;
    if (i < N) {
        int v = rs[i + 1] + bsums[i >> 10];
        rs[i + 1] = v;
        cur[i + 1] = v;
    }
    if (i == 0) { rs[0] = 0; cur[0] = 0; }
}

__global__ void k_fill2(const int* __restrict__ iu_e, int Eiu,
                        const int* __restrict__ ui_e, int Eui,
                        int* __restrict__ cur, int NU,
                        int* __restrict__ csr) {
    int e = blockIdx.x * blockDim.x + threadIdx.x;
    if (e < Eiu) {
        int d = iu_e[Eiu + e];
        int p = atomicAdd(&cur[d], 1);
        csr[p] = iu_e[e];
    } else if (e < Eiu + Eui) {
        int e2 = e - Eiu;
        int d = ui_e[Eui + e2];
        int p = atomicAdd(&cur[NU + d], 1);
        csr[p] = ui_e[e2];
    }
}

// x = bf16( tgt + mean(src rows) ); TWO rows per wave (half-wave each),
// 4-unrolled gather -> up to 8 independent row loads in flight. High-occupancy.
__global__ void k_msg2(const unsigned short* __restrict__ uf_bf,
                       const unsigned short* __restrict__ if_bf,
                       const int* __restrict__ rs, const int* __restrict__ csr,
                       unsigned short* __restrict__ x_u, unsigned short* __restrict__ x_i,
                       int NU, int NI) {
    int pair = (blockIdx.x * blockDim.x + threadIdx.x) >> 6;
    int lane = threadIdx.x & 63;
    int half = lane >> 5;
    int hl   = lane & 31;
    int Ntot = NU + NI;
    int wv = pair * 2 + half;
    if (wv >= Ntot) return;

    const unsigned short* src; const unsigned short* tgt; unsigned short* xo; int w;
    if (wv < NU) { src = if_bf; tgt = uf_bf; xo = x_u; w = wv; }
    else         { src = uf_bf; tgt = if_bf; xo = x_i; w = wv - NU; }

    int s0 = rs[wv], s1 = rs[wv + 1];
    float a0[8] = {}, a1[8] = {}, a2[8] = {}, a3[8] = {};

    int i = s0;
    for (; i + 4 <= s1; i += 4) {
        int e0 = csr[i], e1 = csr[i + 1], e2 = csr[i + 2], e3 = csr[i + 3];
        uint4 r0 = ((const uint4*)(src + (size_t)e0 * D))[hl];
        uint4 r1 = ((const uint4*)(src + (size_t)e1 * D))[hl];
        uint4 r2 = ((const uint4*)(src + (size_t)e2 * D))[hl];
        uint4 r3 = ((const uint4*)(src + (size_t)e3 * D))[hl];
        a0[0] += bf2f_lo(r0.x); a0[1] += bf2f_hi(r0.x); a0[2] += bf2f_lo(r0.y); a0[3] += bf2f_hi(r0.y);
        a0[4] += bf2f_lo(r0.z); a0[5] += bf2f_hi(r0.z); a0[6] += bf2f_lo(r0.w); a0[7] += bf2f_hi(r0.w);
        a1[0] += bf2f_lo(r1.x); a1[1] += bf2f_hi(r1.x); a1[2] += bf2f_lo(r1.y); a1[3] += bf2f_hi(r1.y);
        a1[4] += bf2f_lo(r1.z); a1[5] += bf2f_hi(r1.z); a1[6] += bf2f_lo(r1.w); a1[7] += bf2f_hi(r1.w);
        a2[0] += bf2f_lo(r2.x); a2[1] += bf2f_hi(r2.x); a2[2] += bf2f_lo(r2.y); a2[3] += bf2f_hi(r2.y);
        a2[4] += bf2f_lo(r2.z); a2[5] += bf2f_hi(r2.z); a2[6] += bf2f_lo(r2.w); a2[7] += bf2f_hi(r2.w);
        a3[0] += bf2f_lo(r3.x); a3[1] += bf2f_hi(r3.x); a3[2] += bf2f_lo(r3.y); a3[3] += bf2f_hi(r3.y);
        a3[4] += bf2f_lo(r3.z); a3[5] += bf2f_hi(r3.z); a3[6] += bf2f_lo(r3.w); a3[7] += bf2f_hi(r3.w);
    }
    for (; i < s1; ++i) {
        int e0 = csr[i];
        uint4 r0 = ((const uint4*)(src + (size_t)e0 * D))[hl];
        a0[0] += bf2f_lo(r0.x); a0[1] += bf2f_hi(r0.x); a0[2] += bf2f_lo(r0.y); a0[3] += bf2f_hi(r0.y);
        a0[4] += bf2f_lo(r0.z); a0[5] += bf2f_hi(r0.z); a0[6] += bf2f_lo(r0.w); a0[7] += bf2f_hi(r0.w);
    }

    int cnt = s1 - s0;
    float inv = 1.0f / (float)(cnt > 0 ? cnt : 1);
    uint4 tv = ((const uint4*)(tgt + (size_t)w * D))[hl];
    float x0 = bf2f_lo(tv.x) + (a0[0] + a1[0] + a2[0] + a3[0]) * inv;
    float x1 = bf2f_hi(tv.x) + (a0[1] + a1[1] + a2[1] + a3[1]) * inv;
    float x2 = bf2f_lo(tv.y) + (a0[2] + a1[2] + a2[2] + a3[2]) * inv;
    float x3 = bf2f_hi(tv.y) + (a0[3] + a1[3] + a2[3] + a3[3]) * inv;
    float x4 = bf2f_lo(tv.z) + (a0[4] + a1[4] + a2[4] + a3[4]) * inv;
    float x5 = bf2f_hi(tv.z) + (a0[5] + a1[5] + a2[5] + a3[5]) * inv;
    float x6 = bf2f_lo(tv.w) + (a0[6] + a1[6] + a2[6] + a3[6]) * inv;
    float x7 = bf2f_hi(tv.w) + (a0[7] + a1[7] + a2[7] + a3[7]) * inv;
    uint4 o;
    o.x = pack2(x0, x1); o.y = pack2(x2, x3); o.z = pack2(x4, x5); o.w = pack2(x6, x7);
    ((uint4*)(xo + (size_t)w * D))[hl] = o;
}

// ---- GEMM + bias + ReLU + LayerNorm, SMALL-TILE / HIGH-TLP variant.
// BM2=32 rows per block, 256 threads (4 waves). ~18KB LDS, ~80 VGPR ->
// up to 6+ blocks/CU (24+ waves). B streamed from L2; scattered stores.
__launch_bounds__(256)
__global__ void k_gemm5(const unsigned short* __restrict__ x_u,
                        const unsigned short* __restrict__ x_i,
                        const unsigned short* __restrict__ Wt_u,
                        const unsigned short* __restrict__ Wt_i,
                        const float* __restrict__ bu, const float* __restrict__ bi,
                        const float* __restrict__ gamma, const float* __restrict__ beta,
                        int NU, int NI, int nbU, float* __restrict__ out) {
    __shared__ __align__(16) __hip_bfloat16 As[BM2][LDA];  // 16896 B
    __shared__ float red_s[BM2][4];                         // 512 B
    __shared__ float red_q[BM2][4];                         // 512 B

    int b = blockIdx.x;
    bool isU = b < nbU;
    const unsigned short* X  = isU ? x_u : x_i;
    const unsigned short* Wt = isU ? Wt_u : Wt_i;
    const float* bias        = isU ? bu : bi;
    float* Y                 = isU ? out : out + (size_t)NU * D;
    int N                    = isU ? NU : NI;
    int row0 = (isU ? b : b - nbU) * BM2;

    int t = threadIdx.x;
    int lane = t & 63;
    int w = t >> 6;
    int l15 = lane & 15;
    int l4 = lane >> 4;

    // ---- stage A once: tile = 32 rows x 32 uint4 = 1024 uint4; 4 per thread.
    //      flat uint4 index f = j*256 + t -> row f>>5, col f&31 (coalesced).
    {
        const uint4* Xg = (const uint4*)&X[(size_t)row0 * D];
        #pragma unroll
        for (int j = 0; j < 4; ++j) {
            int f = j * 256 + t;
            int lr = f >> 5;
            int c = f & 31;
            uint4 v = {0, 0, 0, 0};
            if (row0 + lr < N) v = Xg[(size_t)lr * 32 + c];
            *(uint4*)&As[lr][c * 8] = v;
        }
    }

    f32x4 acc[2][4];
    f32x4 zero = {0.f, 0.f, 0.f, 0.f};
    #pragma unroll
    for (int fr = 0; fr < 2; fr++)
        #pragma unroll
        for (int fc = 0; fc < 4; fc++)
            acc[fr][fc] = zero;

    __syncthreads();

    // ---- GEMM: A from LDS, B straight from L2; no barriers in the loop.
    const uint4* Bg = (const uint4*)Wt;   // Wt[col][k]: uint4 index = col*32 + k/8
    int colB = w * 64 + l15;
    #pragma unroll
    for (int ks8 = 0; ks8 < 8; ++ks8) {
        uint4 bq[4];
        #pragma unroll
        for (int fc = 0; fc < 4; ++fc)
            bq[fc] = Bg[(size_t)(colB + fc * 16) * 32 + ks8 * 4 + l4];
        bf16x8 af[2];
        #pragma unroll
        for (int fr = 0; fr < 2; ++fr)
            af[fr] = *(const bf16x8*)&As[fr * 16 + l15][ks8 * 32 + l4 * 8];
        #pragma unroll
        for (int fr = 0; fr < 2; ++fr)
            #pragma unroll
            for (int fc = 0; fc < 4; ++fc)
                acc[fr][fc] = __builtin_amdgcn_mfma_f32_16x16x32_bf16(
                    af[fr], *(bf16x8*)&bq[fc], acc[fr][fc], 0, 0, 0);
    }

    // ---- epilogue: bias + relu + per-row reduce
    float bias_c[4], gam_c[4], bet_c[4];
    #pragma unroll
    for (int fc = 0; fc < 4; fc++) {
        int col = w * 64 + fc * 16 + l15;
        bias_c[fc] = bias[col];
        gam_c[fc]  = gamma[col];
        bet_c[fc]  = beta[col];
    }

    #pragma unroll
    for (int fr = 0; fr < 2; fr++) {
        #pragma unroll
        for (int r = 0; r < 4; r++) {
            int row = fr * 16 + l4 * 4 + r;
            float s = 0.f, q = 0.f;
            #pragma unroll
            for (int fc = 0; fc < 4; fc++) {
                float v = acc[fr][fc][r] + bias_c[fc];
                v = fmaxf(v, 0.f);
                acc[fr][fc][r] = v;
                s += v;
                q += v * v;
            }
            #pragma unroll
            for (int m = 1; m < 16; m <<= 1) {
                s += __shfl_xor(s, m);
                q += __shfl_xor(q, m);
            }
            if (l15 == 0) { red_s[row][w] = s; red_q[row][w] = q; }
        }
    }
    __syncthreads();

    #pragma unroll
    for (int fr = 0; fr < 2; fr++) {
        #pragma unroll
        for (int r = 0; r < 4; r++) {
            int row = fr * 16 + l4 * 4 + r;
            int grow = row0 + row;
            if (grow >= N) continue;
            float s = red_s[row][0] + red_s[row][1] + red_s[row][2] + red_s[row][3];
            float q = red_q[row][0] + red_q[row][1] + red_q[row][2] + red_q[row][3];
            float mu  = s * (1.0f / 256.0f);
            float var = q * (1.0f / 256.0f) - mu * mu;
            float rstd = rsqrtf(var + 1e-5f);
            #pragma unroll
            for (int fc = 0; fc < 4; fc++) {
                int col = w * 64 + fc * 16 + l15;
                Y[(size_t)grow * D + col] = (acc[fr][fc][r] - mu) * rstd * gam_c[fc] + bet_c[fc];
            }
        }
    }
}

// ======================= FALLBACK PATH (R2, small-ws) =======================

__global__ void k_hist(const int* __restrict__ dst, int E, int* __restrict__ deg) {
    int e = blockIdx.x * blockDim.x + threadIdx.x;
    if (e < E) atomicAdd(&deg[dst[e]], 1);
}

__global__ void k_finalize_rs(int N, int* __restrict__ rs, const int* __restrict__ bsums) {
    int i = blockIdx.x * blockDim.x + threadIdx.x;
    if (i < N) rs[i + 1] += bsums[i >> 10];
    if (i == 0) rs[0] = 0;
}

__global__ void k_fill(const int* __restrict__ src, const int* __restrict__ dst, int E,
                       const int* __restrict__ rs, int* __restrict__ cursor,
                       int* __restrict__ csr) {
    int e = blockIdx.x * blockDim.x + threadIdx.x;
    if (e < E) {
        int d = dst[e];
        int p = atomicAdd(&cursor[d], 1);
        csr[rs[d] + p] = src[e];
    }
}

__global__ void k_msg_x(const float* __restrict__ srcf, const float* __restrict__ tgtf,
                        const int* __restrict__ rs, const int* __restrict__ csr,
                        int N, float* __restrict__ xout) {
    int wave = (blockIdx.x * blockDim.x + threadIdx.x) >> 6;
    int lane = threadIdx.x & 63;
    if (wave >= N) return;
    int s0 = rs[wave], s1 = rs[wave + 1];
    float4 acc = make_float4(0.f, 0.f, 0.f, 0.f);
    for (int i = s0; i < s1; i++) {
        int s = csr[i];
        float4 f = *(const float4*)&srcf[(size_t)s * D + lane * 4];
        acc.x += f.x; acc.y += f.y; acc.z += f.z; acc.w += f.w;
    }
    int cnt = s1 - s0;
    float inv = 1.0f / (float)(cnt > 0 ? cnt : 1);
    float4 t = *(const float4*)&tgtf[(size_t)wave * D + lane * 4];
    float4 x;
    x.x = t.x + acc.x * inv;
    x.y = t.y + acc.y * inv;
    x.z = t.z + acc.z * inv;
    x.w = t.w + acc.w * inv;
    *(float4*)&xout[(size_t)wave * D + lane * 4] = x;
}

__global__ void k_wcvt(const float* __restrict__ W0, const float* __restrict__ W1,
                       __hip_bfloat16* __restrict__ Wt0, __hip_bfloat16* __restrict__ Wt1) {
    int b = blockIdx.x;
    const float* W = (b < 256) ? W0 : W1;
    __hip_bfloat16* Wt = (b < 256) ? Wt0 : Wt1;
    int k = b & 255;
    int c = threadIdx.x;
    Wt[(size_t)c * 256 + k] = __float2bfloat16(W[(size_t)k * 256 + c]);
}

__launch_bounds__(256)
__global__ void k_gemm_mfma_ln(const float* __restrict__ X,
                               const __hip_bfloat16* __restrict__ Wt,
                               const float* __restrict__ bias,
                               const float* __restrict__ gamma,
                               const float* __restrict__ beta,
                               int N, float* __restrict__ Y) {
    __shared__ __hip_bfloat16 As[BM][LDK];
    __shared__ __hip_bfloat16 Bs[D][LDK];
    __shared__ float red_s[BM][4];
    __shared__ float red_q[BM][4];

    int t = threadIdx.x;
    int lane = t & 63;
    int w = t >> 6;
    int l15 = lane & 15;
    int l4 = lane >> 4;
    int row0 = blockIdx.x * BM;

    f32x4 acc[4][4];
    f32x4 zero = {0.f, 0.f, 0.f, 0.f};
    #pragma unroll
    for (int fr = 0; fr < 4; fr++)
        #pragma unroll
        for (int fc = 0; fc < 4; fc++)
            acc[fr][fc] = zero;

    for (int k0 = 0; k0 < D; k0 += 64) {
        {
            int i = t >> 2;
            int kq = (t & 3) * 16;
            int r = row0 + i;
            float4 f[4];
            if (r < N) {
                const float4* p = (const float4*)&X[(size_t)r * D + k0 + kq];
                f[0] = p[0]; f[1] = p[1]; f[2] = p[2]; f[3] = p[3];
            } else {
                float4 z4 = make_float4(0.f, 0.f, 0.f, 0.f);
                f[0] = z4; f[1] = z4; f[2] = z4; f[3] = z4;
            }
            __hip_bfloat16 vb[16];
            #pragma unroll
            for (int q = 0; q < 4; q++) {
                vb[q * 4 + 0] = __float2bfloat16(f[q].x);
                vb[q * 4 + 1] = __float2bfloat16(f[q].y);
                vb[q * 4 + 2] = __float2bfloat16(f[q].z);
                vb[q * 4 + 3] = __float2bfloat16(f[q].w);
            }
            *(uint4*)&As[i][kq]     = *(uint4*)&vb[0];
            *(uint4*)&As[i][kq + 8] = *(uint4*)&vb[8];
        }
        #pragma unroll
        for (int pass = 0; pass < 4; pass++) {
            int c = pass * 64 + (t >> 2);
            int kq = (t & 3) * 16;
            const uint4* p = (const uint4*)&Wt[(size_t)c * D + k0 + kq];
            uint4 b0 = p[0], b1 = p[1];
            *(uint4*)&Bs[c][kq]     = b0;
            *(uint4*)&Bs[c][kq + 8] = b1;
        }
        __syncthreads();

        #pragma unroll
        for (int ks = 0; ks < 2; ks++) {
            bf16x8 af[4], bg[4];
            #pragma unroll
            for (int fr = 0; fr < 4; fr++)
                af[fr] = *(const bf16x8*)&As[fr * 16 + l15][ks * 32 + l4 * 8];
            #pragma unroll
            for (int fc = 0; fc < 4; fc++)
                bg[fc] = *(const bf16x8*)&Bs[w * 64 + fc * 16 + l15][ks * 32 + l4 * 8];
            #pragma unroll
            for (int fr = 0; fr < 4; fr++)
                #pragma unroll
                for (int fc = 0; fc < 4; fc++)
                    acc[fr][fc] = __builtin_amdgcn_mfma_f32_16x16x32_bf16(
                        af[fr], bg[fc], acc[fr][fc], 0, 0, 0);
        }
        __syncthreads();
    }

    float bias_c[4], gam_c[4], bet_c[4];
    #pragma unroll
    for (int fc = 0; fc < 4; fc++) {
        int col = w * 64 + fc * 16 + l15;
        bias_c[fc] = bias[col];
        gam_c[fc]  = gamma[col];
        bet_c[fc]  = beta[col];
    }

    #pragma unroll
    for (int fr = 0; fr < 4; fr++) {
        #pragma unroll
        for (int r = 0; r < 4; r++) {
            int row = fr * 16 + l4 * 4 + r;
            float s = 0.f, q = 0.f;
            #pragma unroll
            for (int fc = 0; fc < 4; fc++) {
                float v = acc[fr][fc][r] + bias_c[fc];
                v = fmaxf(v, 0.f);
                acc[fr][fc][r] = v;
                s += v;
                q += v * v;
            }
            #pragma unroll
            for (int m = 1; m < 16; m <<= 1) {
                s += __shfl_xor(s, m);
                q += __shfl_xor(q, m);
            }
            if (l15 == 0) { red_s[row][w] = s; red_q[row][w] = q; }
        }
    }
    __syncthreads();

    #pragma unroll
    for (int fr = 0; fr < 4; fr++) {
        #pragma unroll
        for (int r = 0; r < 4; r++) {
            int row = fr * 16 + l4 * 4 + r;
            int grow = row0 + row;
            if (grow >= N) continue;
            float s = red_s[row][0] + red_s[row][1] + red_s[row][2] + red_s[row][3];
            float q = red_q[row][0] + red_q[row][1] + red_q[row][2] + red_q[row][3];
            float mu  = s * (1.0f / 256.0f);
            float var = q * (1.0f / 256.0f) - mu * mu;
            float rstd = rsqrtf(var + 1e-5f);
            #pragma unroll
            for (int fc = 0; fc < 4; fc++) {
                int col = w * 64 + fc * 16 + l15;
                Y[(size_t)grow * D + col] = (acc[fr][fc][r] - mu) * rstd * gam_c[fc] + bet_c[fc];
            }
        }
    }
}

// ======================= launch =======================

extern "C" void kernel_launch(void* const* d_in, const int* in_sizes, int n_in,
                              void* d_out, int out_size, void* d_ws, size_t ws_size,
                              hipStream_t stream) {
    const float* uf    = (const float*)d_in[0];
    const float* itf   = (const float*)d_in[1];
    const int*   ui_e  = (const int*)d_in[2];   // [2, Eui] user->item
    const int*   iu_e  = (const int*)d_in[3];   // [2, Eiu] item->user
    const float* Wu    = (const float*)d_in[4];
    const float* bu    = (const float*)d_in[5];
    const float* Wi    = (const float*)d_in[6];
    const float* bi    = (const float*)d_in[7];
    const float* gamma = (const float*)d_in[8];
    const float* beta  = (const float*)d_in[9];

    int NU  = in_sizes[0] / D;
    int NI  = in_sizes[1] / D;
    int Eui = in_sizes[2] / 2;
    int Eiu = in_sizes[3] / 2;
    int Nmax = NU > NI ? NU : NI;
    int Ntot = NU + NI;
    int Etot = Eiu + Eui;

    float* out   = (float*)d_out;
    size_t nfU = (size_t)NU * D;
    size_t nfI = (size_t)NI * D;
    size_t nfTot = nfU + nfI;

    // fast-path ws layout
    unsigned short* uf_bf = (unsigned short*)d_ws;     // nfU
    unsigned short* if_bf = uf_bf + nfU;               // nfI
    unsigned short* x_u   = if_bf + nfI;               // nfU
    unsigned short* x_i   = x_u + nfU;                 // nfI
    unsigned short* Wt_u2 = x_i + nfI;                 // 65536
    unsigned short* Wt_i2 = Wt_u2 + 65536;             // 65536
    int* deg2  = (int*)(Wt_i2 + 65536);                // Ntot
    int* rs2   = deg2 + Ntot;                          // Ntot+1
    int* cur2  = rs2 + Ntot + 1;                       // Ntot+1
    int* bsums = cur2 + Ntot + 1;                      // 1024
    int* csr2  = bsums + 1024;                         // Etot
    size_t needed = (size_t)((char*)(csr2 + Etot) - (char*)d_ws);

    if (ws_size >= needed) {
        int nbF = (int)((nfTot + 2047) / 2048);
        int nbH = (Etot + 255) / 256;
        hipMemsetAsync(deg2, 0, (size_t)Ntot * sizeof(int), stream);
        k_prep<<<nbF + 512 + nbH, 256, 0, stream>>>(uf, itf, Wu, Wi, uf_bf, Wt_u2, Wt_i2,
                                                    iu_e, Eiu, ui_e, Eui, deg2, NU,
                                                    nfU, nfTot, nbF);
        int nb = (Ntot + 1023) / 1024;
        k_scan_block<<<nb, 1024, 0, stream>>>(deg2, Ntot, rs2, bsums);
        k_scan_sums<<<1, 1024, 0, stream>>>(bsums, nb);
        k_finalize<<<(Ntot + 255) / 256, 256, 0, stream>>>(Ntot, rs2, cur2, bsums);
        k_fill2<<<nbH, 256, 0, stream>>>(iu_e, Eiu, ui_e, Eui, cur2, NU, csr2);
        int pairs = (Ntot + 1) / 2;
        k_msg2<<<(pairs + 3) / 4, 256, 0, stream>>>(uf_bf, if_bf, rs2, csr2, x_u, x_i, NU, NI);
        int nbU = (NU + BM2 - 1) / BM2;
        int nbI = (NI + BM2 - 1) / BM2;
        k_gemm5<<<nbU + nbI, 256, 0, stream>>>(x_u, x_i, Wt_u2, Wt_i2, bu, bi, gamma, beta,
                                               NU, NI, nbU, out);
        return;
    }

    // ---------- fallback: R2 path (needs ~2.2 MB ws) ----------
    float* u_out = out;
    float* i_out = out + nfU;
    __hip_bfloat16* Wt_u = (__hip_bfloat16*)d_ws;
    __hip_bfloat16* Wt_i = Wt_u + 256 * 256;
    int* deg    = (int*)(Wt_i + 256 * 256);
    int* rs     = deg + Nmax;
    int* bs     = rs + Nmax + 1;
    int* cursor = bs + 1024;
    int* csr    = cursor + Nmax;

    k_wcvt<<<512, 256, 0, stream>>>(Wu, Wi, Wt_u, Wt_i);

    auto run_side = [&](const float* srcf, const float* tgtf, const int* edges, int E,
                        int N, const __hip_bfloat16* Wt, const float* bias, float* y) {
        const int* esrc = edges;
        const int* edst = edges + E;
        hipMemsetAsync(deg, 0, (size_t)N * sizeof(int), stream);
        hipMemsetAsync(cursor, 0, (size_t)N * sizeof(int), stream);
        k_hist<<<(E + 255) / 256, 256, 0, stream>>>(edst, E, deg);
        int nb = (N + 1023) / 1024;
        k_scan_block<<<nb, 1024, 0, stream>>>(deg, N, rs, bs);
        k_scan_sums<<<1, 1024, 0, stream>>>(bs, nb);
        k_finalize_rs<<<(N + 255) / 256, 256, 0, stream>>>(N, rs, bs);
        k_fill<<<(E + 255) / 256, 256, 0, stream>>>(esrc, edst, E, rs, cursor, csr);
        k_msg_x<<<(N + 3) / 4, 256, 0, stream>>>(srcf, tgtf, rs, csr, N, y);
        k_gemm_mfma_ln<<<(N + BM - 1) / BM, 256, 0, stream>>>(y, Wt, bias, gamma, beta, N, y);
    };

    run_side(itf, uf, iu_e, Eiu, NU, Wt_u, bu, u_out);
    run_side(uf, itf, ui_e, Eui, NI, Wt_i, bi, i_out);
}